// Round 8
// baseline (29.827 us; speedup 1.0000x reference)
//
#include <hip/hip_runtime.h>
#include <float.h>

#define WINDOW  500
#define NQUADS  125
#define NSHIFT  125
#define WPS     4              // windows per stage (one per wave)
#define NSTG    4              // stages per block
#define WPBLK   (WPS * NSTG)   // 16 windows per block
#define CHUNK_Q 500            // quads per stage per input (4 win * 125)
#define CPAD_Q  512            // padded to 8 DMA instrs * 64 lanes

// ---- DPP cross-lane primitives (VALU, no LDS traffic) ---------------------
template <int CTRL, int RM>
__device__ __forceinline__ float dpp_add_step(float x) {
    int t = __builtin_amdgcn_update_dpp(0, __float_as_int(x), CTRL, RM, 0xf, false);
    return x + __int_as_float(t);
}
__device__ __forceinline__ float scan64_add(float x) {
    x = dpp_add_step<0x111, 0xf>(x);   // row_shr:1
    x = dpp_add_step<0x112, 0xf>(x);   // row_shr:2
    x = dpp_add_step<0x114, 0xf>(x);   // row_shr:4
    x = dpp_add_step<0x118, 0xf>(x);   // row_shr:8
    x = dpp_add_step<0x142, 0xa>(x);   // row_bcast:15
    x = dpp_add_step<0x143, 0xc>(x);   // row_bcast:31
    return x;                          // lane63 = wave total
}
template <int CTRL, int RM>
__device__ __forceinline__ float dpp_min_step(float x) {
    int t = __builtin_amdgcn_update_dpp(0x7f800000, __float_as_int(x), CTRL, RM, 0xf, false);
    return fminf(x, __int_as_float(t));
}
__device__ __forceinline__ float wave_min64(float x) {
    x = dpp_min_step<0x111, 0xf>(x);
    x = dpp_min_step<0x112, 0xf>(x);
    x = dpp_min_step<0x114, 0xf>(x);
    x = dpp_min_step<0x118, 0xf>(x);
    x = dpp_min_step<0x142, 0xa>(x);
    x = dpp_min_step<0x143, 0xc>(x);
    return __int_as_float(__builtin_amdgcn_readlane(__float_as_int(x), 63));
}
__device__ __forceinline__ float rl63(float x) {
    return __int_as_float(__builtin_amdgcn_readlane(__float_as_int(x), 63));
}
__device__ __forceinline__ float frcp(float x) {
    float r = __builtin_amdgcn_rcpf(x);
    return r * (2.0f - x * r);
}

__device__ __forceinline__ float ccc_eval(float Sp, float Spp, float Spg,
                                          float m_g, float var_g) {
    const float invW   = 1.0f / (float)WINDOW;
    const float invWm1 = 1.0f / (float)(WINDOW - 1);
    float m_p   = Sp * invW;
    float var_p = (Spp - (float)WINDOW * m_p * m_p) * invWm1;
    float cov   = Spg * invW - m_p * m_g;
    float d     = m_g - m_p;
    return 2.0f * cov * frcp(var_g + var_p + d * d);
}

// ---- async staging: global -> LDS DMA, no VGPR landing --------------------
typedef const __attribute__((address_space(1))) void* gas_ptr;
typedef __attribute__((address_space(3))) void*       las_ptr;

// 4 KB per wave per stage: 4 x (64 lanes x 16 B)
__device__ __forceinline__ void stage4(const float4* __restrict__ src4,
                                       float* dst,      // LDS chunk base (generic)
                                       int cq,          // chunk start quad
                                       int qofs,        // 0 or 256 (wave half)
                                       int maxq, int lane)
{
    #pragma unroll
    for (int i = 0; i < 4; ++i) {
        int q = cq + qofs + i * 64 + lane;
        q = (q > maxq) ? maxq : q;
        __builtin_amdgcn_global_load_lds(
            (gas_ptr)(const void*)(src4 + q),
            (las_ptr)(void*)(dst + (qofs + i * 64) * 4),
            16, 0, 0);
    }
}

#define VMW(n)  asm volatile("s_waitcnt vmcnt(" #n ")" ::: "memory")
#define SBAR()  do { __builtin_amdgcn_s_barrier();               \
                     __builtin_amdgcn_sched_barrier(0);          \
                     asm volatile("" ::: "memory"); } while (0)

// Per-window compute from LDS; returns wave-uniform min over 125 shifts.
__device__ __forceinline__ float compute_win_lds(const float* lp, const float* lg,
                                                 int lane)
{
    const float4* p4 = (const float4*)lp;
    const float4* g4 = (const float4*)lg;
    const bool tail = (lane < NQUADS - 64);        // lane < 61
    const int  i1   = 64 + (tail ? lane : 0);
    float4 pa = p4[lane], ga = g4[lane];
    float4 pb = p4[i1],   gb = g4[i1];
    if (!tail) { pb = make_float4(0.f,0.f,0.f,0.f); gb = make_float4(0.f,0.f,0.f,0.f); }

    const float qp  = pa.x + pa.y + pa.z + pa.w;
    const float qpp = pa.x*pa.x + pa.y*pa.y + pa.z*pa.z + pa.w*pa.w;
    const float qpg = pa.x*ga.x + pa.y*ga.y + pa.z*ga.z + pa.w*ga.w;
    const float r1p  = pb.x + pb.y + pb.z + pb.w;
    const float r1pp = pb.x*pb.x + pb.y*pb.y + pb.z*pb.z + pb.w*pb.w;
    const float r1pg = pb.x*gb.x + pb.y*gb.y + pb.z*gb.z + pb.w*gb.w;
    const float lgs  = ga.x + ga.y + ga.z + ga.w + gb.x + gb.y + gb.z + gb.w;
    const float lgg  = ga.x*ga.x + ga.y*ga.y + ga.z*ga.z + ga.w*ga.w
                     + gb.x*gb.x + gb.y*gb.y + gb.z*gb.z + gb.w*gb.w;

    float c_p  = scan64_add(qp);
    float c_pp = scan64_add(qpp);
    float c_pg = scan64_add(qpg);
    const float sp  = rl63(c_p)  + rl63(scan64_add(r1p));
    const float spp = rl63(c_pp) + rl63(scan64_add(r1pp));
    const float spg = rl63(c_pg) + rl63(scan64_add(r1pg));
    const float sg  = rl63(scan64_add(lgs));
    const float sgg = rl63(scan64_add(lgg));

    const float invW   = 1.0f / (float)WINDOW;
    const float invWm1 = 1.0f / (float)(WINDOW - 1);
    const float m_g   = sg * invW;
    const float var_g = (sgg - (float)WINDOW * m_g * m_g) * invWm1;

    float cmin = FLT_MAX;
    if (lane < 32) {
        float Sp  = sp  - (c_p  - qp);
        float Spp = spp - (c_pp - qpp);
        float Spg = spg - (c_pg - qpg);
        const int base = lane * 4;
        cmin = ccc_eval(Sp, Spp, Spg, m_g, var_g);                    // r=0
        Sp -= pa.x; Spp -= pa.x*pa.x; Spg -= pa.x*ga.x;               // r=1
        if (base + 1 < NSHIFT) cmin = fminf(cmin, ccc_eval(Sp, Spp, Spg, m_g, var_g));
        Sp -= pa.y; Spp -= pa.y*pa.y; Spg -= pa.y*ga.y;               // r=2
        if (base + 2 < NSHIFT) cmin = fminf(cmin, ccc_eval(Sp, Spp, Spg, m_g, var_g));
        Sp -= pa.z; Spp -= pa.z*pa.z; Spg -= pa.z*ga.z;               // r=3
        if (base + 3 < NSHIFT) cmin = fminf(cmin, ccc_eval(Sp, Spp, Spg, m_g, var_g));
    }
    return wave_min64(cmin);
}

template <bool TWO_STAGE>
__global__ __launch_bounds__(256, 5) void window_ccc_kernel(
    const float4* __restrict__ pred4,
    const float4* __restrict__ gt4,
    float* __restrict__ block_out,
    int num_wins)
{
    __shared__ float lds_p[2][CPAD_Q * 4];   // 2 x 8192 B
    __shared__ float lds_g[2][CPAD_Q * 4];   // 2 x 8192 B
    __shared__ float s_sum[WPS];

    const int wave = threadIdx.x >> 6;
    const int lane = threadIdx.x & 63;
    const int blk  = blockIdx.x;
    const int maxq = num_wins * NQUADS - 1;
    const int bq   = blk * (WPBLK * NQUADS);       // block chunk start (quads)

    const float4* ssrc = (wave & 2) ? gt4 : pred4; // waves 0,1 stage p; 2,3 stage g
    const int     qofs = (wave & 1) ? 256 : 0;

    #define STAGE(s, b)                                                     \
        stage4(ssrc, (wave & 2) ? lds_g[b] : lds_p[b],                      \
               bq + (s) * CHUNK_Q, qofs, maxq, lane)

    STAGE(0, 0);
    STAGE(1, 1);

    float ws = 0.f;
    int w = blk * WPBLK + wave;                    // this wave's window, stage 0

    VMW(4); SBAR();                                // stage0 landed everywhere
    { float cm = compute_win_lds(lds_p[0] + wave * WINDOW,
                                 lds_g[0] + wave * WINDOW, lane);
      if (w < num_wins) ws += cm; }
    SBAR();                                        // all waves done reading buf0
    STAGE(2, 0);
    VMW(4); SBAR();                                // stage1 landed
    { float cm = compute_win_lds(lds_p[1] + wave * WINDOW,
                                 lds_g[1] + wave * WINDOW, lane);
      if (w + WPS < num_wins) ws += cm; }
    SBAR();                                        // done reading buf1
    STAGE(3, 1);
    VMW(4); SBAR();                                // stage2 landed
    { float cm = compute_win_lds(lds_p[0] + wave * WINDOW,
                                 lds_g[0] + wave * WINDOW, lane);
      if (w + 2 * WPS < num_wins) ws += cm; }
    VMW(0); SBAR();                                // stage3 landed
    { float cm = compute_win_lds(lds_p[1] + wave * WINDOW,
                                 lds_g[1] + wave * WINDOW, lane);
      if (w + 3 * WPS < num_wins) ws += cm; }
    #undef STAGE

    if (lane == 0) s_sum[wave] = ws;
    __syncthreads();
    if (threadIdx.x == 0) {
        float s = s_sum[0] + s_sum[1] + s_sum[2] + s_sum[3];
        if (TWO_STAGE) block_out[blockIdx.x] = s;
        else           atomicAdd(block_out, s);
    }
}

__global__ __launch_bounds__(256) void window_ccc_finalize(
    const float* __restrict__ block_sums, int nblocks,
    float* __restrict__ out, int num_wins)
{
    float s = 0.f;
    for (int i = threadIdx.x; i < nblocks; i += 256) s += block_sums[i];
    #pragma unroll
    for (int off = 32; off >= 1; off >>= 1) s += __shfl_xor(s, off);
    __shared__ float ws[4];
    const int wave = threadIdx.x >> 6, lane = threadIdx.x & 63;
    if (lane == 0) ws[wave] = s;
    __syncthreads();
    if (threadIdx.x == 0)
        out[0] = 1.0f - (ws[0] + ws[1] + ws[2] + ws[3]) / (float)num_wins;
}

extern "C" void kernel_launch(void* const* d_in, const int* in_sizes, int n_in,
                              void* d_out, int out_size, void* d_ws, size_t ws_size,
                              hipStream_t stream) {
    const float4* pred4 = (const float4*)d_in[0];
    const float4* gt4   = (const float4*)d_in[1];
    float* out = (float*)d_out;
    float* ws  = (float*)d_ws;

    const int L = in_sizes[0];
    const int num_wins = L / WINDOW;
    const int nblocks  = (num_wins + WPBLK - 1) / WPBLK;   // 2048

    if (ws_size >= (size_t)nblocks * sizeof(float)) {
        window_ccc_kernel<true><<<nblocks, 256, 0, stream>>>(pred4, gt4, ws, num_wins);
        window_ccc_finalize<<<1, 256, 0, stream>>>(ws, nblocks, out, num_wins);
    } else {
        hipMemsetAsync(ws, 0, sizeof(float), stream);
        window_ccc_kernel<false><<<nblocks, 256, 0, stream>>>(pred4, gt4, ws, num_wins);
        window_ccc_finalize<<<1, 256, 0, stream>>>(ws, 1, out, num_wins);
    }
}